// Round 1
// baseline (1119.657 us; speedup 1.0000x reference)
//
#include <hip/hip_runtime.h>
#include <cstdint>
#include <cstddef>

#define BB 128
#define NN 2048
#define HH 768
#define H2 1536
#define SSPLIT 16
#define CHUNK (NN / SSPLIT)   // 128 rows per pooling block
#define RT 16                 // rows per mlp1 block

// ---------------------------------------------------------------------------
// Kernel A: mean-pool over N. grid (B, SSPLIT) x 192 threads.
// Each thread owns one float4 column slice (192*4 = 768 = H), sums CHUNK rows
// serially (coalesced 16B/lane loads), then 4 atomicAdds into pooled[b*H+...].
// pooled must be pre-zeroed. Division by N is folded into kernel B.
// ---------------------------------------------------------------------------
__global__ __launch_bounds__(192) void pool_kernel(const float* __restrict__ v,
                                                   float* __restrict__ pooled) {
    const int b = blockIdx.x, s = blockIdx.y, t = threadIdx.x;
    const float4* vp =
        reinterpret_cast<const float4*>(v + ((size_t)b * NN + (size_t)s * CHUNK) * HH) + t;
    float4 acc = make_float4(0.f, 0.f, 0.f, 0.f);
#pragma unroll 4
    for (int n = 0; n < CHUNK; ++n) {
        float4 x = vp[(size_t)n * (HH / 4)];
        acc.x += x.x; acc.y += x.y; acc.z += x.z; acc.w += x.w;
    }
    float* p = pooled + (size_t)b * HH + t * 4;
    atomicAdd(p + 0, acc.x);
    atomicAdd(p + 1, acc.y);
    atomicAdd(p + 2, acc.z);
    atomicAdd(p + 3, acc.w);
}

// ---------------------------------------------------------------------------
// Kernel B: h = gelu(pooled/N @ W1 + b1). grid (H2/256 j-tiles, B/RT row-tiles)
// x 256 threads. 16 pooled rows staged in LDS (48 KB); thread j accumulates 16
// rows, k unrolled by 4 (ds_read_b128 broadcasts, 64 FMA per 4 W1 loads).
// ---------------------------------------------------------------------------
__global__ __launch_bounds__(256) void mlp1_kernel(const float* __restrict__ pooled,
                                                   const float* __restrict__ W1,
                                                   const float* __restrict__ b1,
                                                   float* __restrict__ hbuf) {
    __shared__ float lds[RT * HH];
    const int j0 = blockIdx.x * 256, r0 = blockIdx.y * RT, tid = threadIdx.x;
    const float invN = 1.0f / (float)NN;

    const float4* src = reinterpret_cast<const float4*>(pooled + (size_t)r0 * HH);
    float4* dst = reinterpret_cast<float4*>(lds);
    for (int i = tid; i < RT * HH / 4; i += 256) {
        float4 x = src[i];
        x.x *= invN; x.y *= invN; x.z *= invN; x.w *= invN;
        dst[i] = x;
    }
    __syncthreads();

    const int j = j0 + tid;
    float acc[RT];
#pragma unroll
    for (int r = 0; r < RT; ++r) acc[r] = 0.f;

    const float* w = W1 + j;
    for (int k = 0; k < HH; k += 4) {
        const float w0 = w[(size_t)(k + 0) * H2];
        const float w1 = w[(size_t)(k + 1) * H2];
        const float w2 = w[(size_t)(k + 2) * H2];
        const float w3 = w[(size_t)(k + 3) * H2];
#pragma unroll
        for (int r = 0; r < RT; ++r) {
            float4 p = dst[(r * HH + k) >> 2];  // LDS broadcast, conflict-free
            acc[r] = fmaf(p.x, w0, acc[r]);
            acc[r] = fmaf(p.y, w1, acc[r]);
            acc[r] = fmaf(p.z, w2, acc[r]);
            acc[r] = fmaf(p.w, w3, acc[r]);
        }
    }

    const float bj = b1[j];
#pragma unroll
    for (int r = 0; r < RT; ++r) {
        float hv = acc[r] + bj;
        float g = 0.5f * hv * (1.0f + erff(hv * 0.70710678118654752f));  // exact GELU
        hbuf[(size_t)(r0 + r) * H2 + j] = g;
    }
}

// ---------------------------------------------------------------------------
// Kernel C: LayerNorm + W2 dot + round/clip/one-hot. One block per batch row.
// ---------------------------------------------------------------------------
__device__ inline float block_sum(float v, float* sbuf, int tid) {
#pragma unroll
    for (int off = 32; off > 0; off >>= 1) v += __shfl_down(v, off, 64);
    if ((tid & 63) == 0) sbuf[tid >> 6] = v;
    __syncthreads();
    if (tid == 0) sbuf[0] = sbuf[0] + sbuf[1] + sbuf[2] + sbuf[3];
    __syncthreads();
    float r = sbuf[0];
    __syncthreads();  // safe reuse of sbuf by the next reduction
    return r;
}

__global__ __launch_bounds__(256) void head_kernel(const float* __restrict__ hbuf,
                                                   const float* __restrict__ gamma,
                                                   const float* __restrict__ beta,
                                                   const float* __restrict__ W2,
                                                   const float* __restrict__ b2,
                                                   float* __restrict__ out) {
    __shared__ float sbuf[4];
    __shared__ int said;
    const int b = blockIdx.x, tid = threadIdx.x;
    const float* row = hbuf + (size_t)b * H2;

    float v[6];
#pragma unroll
    for (int i = 0; i < 6; ++i) v[i] = row[tid + i * 256];

    float s = 0.f;
#pragma unroll
    for (int i = 0; i < 6; ++i) s += v[i];
    const float mu = block_sum(s, sbuf, tid) * (1.0f / (float)H2);

    float sq = 0.f;
#pragma unroll
    for (int i = 0; i < 6; ++i) {
        float d = v[i] - mu;
        sq = fmaf(d, d, sq);
    }
    const float var = block_sum(sq, sbuf, tid) * (1.0f / (float)H2);
    const float rstd = rsqrtf(var + 1e-5f);

    float d = 0.f;
#pragma unroll
    for (int i = 0; i < 6; ++i) {
        int j = tid + i * 256;
        float y = (v[i] - mu) * rstd * gamma[j] + beta[j];
        d = fmaf(y, W2[j], d);
    }
    const float pred = block_sum(d, sbuf, tid) + b2[0];

    if (tid == 0) {
        out[b] = pred;                         // pred output [B,1]
        float a = rintf(pred);                 // round-half-even == jnp.round
        a = fminf(fmaxf(a, 0.0f), 15.0f);      // clip to [0, 15]
        said = (int)a;
    }
    __syncthreads();
    if (tid < 16) out[BB + b * 16 + tid] = (tid == said) ? 1.0f : 0.0f;
}

// ---------------------------------------------------------------------------
extern "C" void kernel_launch(void* const* d_in, const int* in_sizes, int n_in,
                              void* d_out, int out_size, void* d_ws, size_t ws_size,
                              hipStream_t stream) {
    const float* v_emb = (const float*)d_in[0];
    const float* W1    = (const float*)d_in[1];
    const float* b1    = (const float*)d_in[2];
    const float* gamma = (const float*)d_in[3];
    const float* beta  = (const float*)d_in[4];
    const float* W2    = (const float*)d_in[5];
    const float* b2    = (const float*)d_in[6];
    float* out = (float*)d_out;

    float* pooled = (float*)d_ws;               // B*H floats   (393 KB)
    float* hbuf   = pooled + (size_t)BB * HH;   // B*2H floats  (786 KB)

    // zero the atomic accumulator (ws is poisoned 0xAA before every launch)
    hipMemsetAsync(d_ws, 0, (size_t)BB * HH * sizeof(float), stream);

    pool_kernel<<<dim3(BB, SSPLIT), 192, 0, stream>>>(v_emb, pooled);
    mlp1_kernel<<<dim3(H2 / 256, BB / RT), 256, 0, stream>>>(pooled, W1, b1, hbuf);
    head_kernel<<<BB, 256, 0, stream>>>(hbuf, gamma, beta, W2, b2, out);
}

// Round 2
// 1073.671 us; speedup vs baseline: 1.0428x; 1.0428x over previous
//
#include <hip/hip_runtime.h>
#include <cstdint>
#include <cstddef>

#define BB 128
#define NN 2048
#define HH 768
#define H2 1536
#define SSPLIT 16
#define CHUNK (NN / SSPLIT)   // 128 rows per pooling block
#define RT 2                  // batch rows per mlp1 block
#define JT 512                // columns per mlp1 block (2 per thread)

// ---------------------------------------------------------------------------
// Kernel A: mean-pool over N. grid (B, SSPLIT) x 192 threads.
// Each thread owns one float4 column slice (192*4 = 768 = H), sums CHUNK rows
// serially (coalesced 16B/lane loads), scales by 1/N, then 4 atomicAdds into
// pooled[b*H + ...]. pooled must be pre-zeroed.
// ---------------------------------------------------------------------------
__global__ __launch_bounds__(192) void pool_kernel(const float* __restrict__ v,
                                                   float* __restrict__ pooled) {
    const int b = blockIdx.x, s = blockIdx.y, t = threadIdx.x;
    const float4* vp =
        reinterpret_cast<const float4*>(v + ((size_t)b * NN + (size_t)s * CHUNK) * HH) + t;
    float4 acc = make_float4(0.f, 0.f, 0.f, 0.f);
#pragma unroll 8
    for (int n = 0; n < CHUNK; ++n) {
        float4 x = vp[(size_t)n * (HH / 4)];
        acc.x += x.x; acc.y += x.y; acc.z += x.z; acc.w += x.w;
    }
    const float invN = 1.0f / (float)NN;
    float* p = pooled + (size_t)b * HH + t * 4;
    atomicAdd(p + 0, acc.x * invN);
    atomicAdd(p + 1, acc.y * invN);
    atomicAdd(p + 2, acc.z * invN);
    atomicAdd(p + 3, acc.w * invN);
}

// ---------------------------------------------------------------------------
// Kernel B: h = gelu(pooled @ W1 + b1), pooled already mean-scaled.
// grid (H2/JT = 3, B/RT = 64) x 256 threads. RT=2 rows staged in LDS (6 KB);
// each thread owns 2 columns (j, j+256). Per k-quad: 2 ds_read_b128
// broadcasts + 8 coalesced W1 loads + 32 FMAs. 192 blocks -> 192 CUs.
// ---------------------------------------------------------------------------
__global__ __launch_bounds__(256) void mlp1_kernel(const float* __restrict__ pooled,
                                                   const float* __restrict__ W1,
                                                   const float* __restrict__ b1,
                                                   float* __restrict__ hbuf) {
    __shared__ float4 lds[RT * HH / 4];   // RT rows of pooled
    const int j0 = blockIdx.x * JT, r0 = blockIdx.y * RT, tid = threadIdx.x;

    const float4* src = reinterpret_cast<const float4*>(pooled + (size_t)r0 * HH);
    for (int i = tid; i < RT * HH / 4; i += 256) lds[i] = src[i];
    __syncthreads();

    const int ja = j0 + tid;          // column A
    const int jb = ja + 256;          // column B
    float acca[RT], accb[RT];
#pragma unroll
    for (int r = 0; r < RT; ++r) { acca[r] = 0.f; accb[r] = 0.f; }

    const float* wa = W1 + ja;
    const float* wb = W1 + jb;
    for (int k = 0; k < HH; k += 4) {
        const float wa0 = wa[(size_t)(k + 0) * H2];
        const float wa1 = wa[(size_t)(k + 1) * H2];
        const float wa2 = wa[(size_t)(k + 2) * H2];
        const float wa3 = wa[(size_t)(k + 3) * H2];
        const float wb0 = wb[(size_t)(k + 0) * H2];
        const float wb1 = wb[(size_t)(k + 1) * H2];
        const float wb2 = wb[(size_t)(k + 2) * H2];
        const float wb3 = wb[(size_t)(k + 3) * H2];
#pragma unroll
        for (int r = 0; r < RT; ++r) {
            float4 p = lds[r * (HH / 4) + (k >> 2)];   // broadcast, conflict-free
            acca[r] = fmaf(p.x, wa0, acca[r]);
            acca[r] = fmaf(p.y, wa1, acca[r]);
            acca[r] = fmaf(p.z, wa2, acca[r]);
            acca[r] = fmaf(p.w, wa3, acca[r]);
            accb[r] = fmaf(p.x, wb0, accb[r]);
            accb[r] = fmaf(p.y, wb1, accb[r]);
            accb[r] = fmaf(p.z, wb2, accb[r]);
            accb[r] = fmaf(p.w, wb3, accb[r]);
        }
    }

    const float ba = b1[ja], bb = b1[jb];
#pragma unroll
    for (int r = 0; r < RT; ++r) {
        float ha = acca[r] + ba;
        float hb = accb[r] + bb;
        float ga = 0.5f * ha * (1.0f + erff(ha * 0.70710678118654752f));  // exact GELU
        float gb = 0.5f * hb * (1.0f + erff(hb * 0.70710678118654752f));
        hbuf[(size_t)(r0 + r) * H2 + ja] = ga;
        hbuf[(size_t)(r0 + r) * H2 + jb] = gb;
    }
}

// ---------------------------------------------------------------------------
// Kernel C: LayerNorm + W2 dot + round/clip/one-hot. One block per batch row.
// ---------------------------------------------------------------------------
__device__ inline float block_sum(float v, float* sbuf, int tid) {
#pragma unroll
    for (int off = 32; off > 0; off >>= 1) v += __shfl_down(v, off, 64);
    if ((tid & 63) == 0) sbuf[tid >> 6] = v;
    __syncthreads();
    if (tid == 0) sbuf[0] = sbuf[0] + sbuf[1] + sbuf[2] + sbuf[3];
    __syncthreads();
    float r = sbuf[0];
    __syncthreads();  // safe reuse of sbuf by the next reduction
    return r;
}

__global__ __launch_bounds__(256) void head_kernel(const float* __restrict__ hbuf,
                                                   const float* __restrict__ gamma,
                                                   const float* __restrict__ beta,
                                                   const float* __restrict__ W2,
                                                   const float* __restrict__ b2,
                                                   float* __restrict__ out) {
    __shared__ float sbuf[4];
    __shared__ int said;
    const int b = blockIdx.x, tid = threadIdx.x;
    const float* row = hbuf + (size_t)b * H2;

    float v[6];
#pragma unroll
    for (int i = 0; i < 6; ++i) v[i] = row[tid + i * 256];

    float s = 0.f;
#pragma unroll
    for (int i = 0; i < 6; ++i) s += v[i];
    const float mu = block_sum(s, sbuf, tid) * (1.0f / (float)H2);

    float sq = 0.f;
#pragma unroll
    for (int i = 0; i < 6; ++i) {
        float d = v[i] - mu;
        sq = fmaf(d, d, sq);
    }
    const float var = block_sum(sq, sbuf, tid) * (1.0f / (float)H2);
    const float rstd = rsqrtf(var + 1e-5f);

    float d = 0.f;
#pragma unroll
    for (int i = 0; i < 6; ++i) {
        int j = tid + i * 256;
        float y = (v[i] - mu) * rstd * gamma[j] + beta[j];
        d = fmaf(y, W2[j], d);
    }
    const float pred = block_sum(d, sbuf, tid) + b2[0];

    if (tid == 0) {
        out[b] = pred;                         // pred output [B,1]
        float a = rintf(pred);                 // round-half-even == jnp.round
        a = fminf(fmaxf(a, 0.0f), 15.0f);      // clip to [0, 15]
        said = (int)a;
    }
    __syncthreads();
    if (tid < 16) out[BB + b * 16 + tid] = (tid == said) ? 1.0f : 0.0f;
}

// ---------------------------------------------------------------------------
extern "C" void kernel_launch(void* const* d_in, const int* in_sizes, int n_in,
                              void* d_out, int out_size, void* d_ws, size_t ws_size,
                              hipStream_t stream) {
    const float* v_emb = (const float*)d_in[0];
    const float* W1    = (const float*)d_in[1];
    const float* b1    = (const float*)d_in[2];
    const float* gamma = (const float*)d_in[3];
    const float* beta  = (const float*)d_in[4];
    const float* W2    = (const float*)d_in[5];
    const float* b2    = (const float*)d_in[6];
    float* out = (float*)d_out;

    float* pooled = (float*)d_ws;               // B*H floats   (393 KB)
    float* hbuf   = pooled + (size_t)BB * HH;   // B*2H floats  (786 KB)

    // zero the atomic accumulator (ws is poisoned 0xAA before every launch)
    hipMemsetAsync(d_ws, 0, (size_t)BB * HH * sizeof(float), stream);

    pool_kernel<<<dim3(BB, SSPLIT), 192, 0, stream>>>(v_emb, pooled);
    mlp1_kernel<<<dim3(H2 / JT, BB / RT), 256, 0, stream>>>(pooled, W1, b1, hbuf);
    head_kernel<<<BB, 256, 0, stream>>>(hbuf, gamma, beta, W2, b2, out);
}